// Round 1
// baseline (910.902 us; speedup 1.0000x reference)
//
#include <hip/hip_runtime.h>
#include <hip/hip_bf16.h>

// VGG16 ROI head: roi_pool -> fc6(relu) -> fc7(relu) -> {cls, score}
// M=128 rows everywhere. Weight-streaming memory-bound: fc6 weights are 411 MB fp32.
// Strategy: bf16 MFMA (16x16x32), converting W fp32->bf16 in-register inside the GEMM
// (weights are read exactly once from HBM), split-K partials + reduction epilogue.

typedef short short8 __attribute__((ext_vector_type(8)));   // 8 x bf16 bits
typedef float f32x4 __attribute__((ext_vector_type(4)));

#define K6 25088
#define N6 4096
#define NHD 128   // heads padded to 128 cols (84 cls + 21 score + 23 zero)

// round-half-up fp32 -> bf16 (2 VALU ops; bias negligible vs threshold)
static __device__ inline short f2bf(float f) {
    unsigned u = __builtin_bit_cast(unsigned, f);
    u += 0x8000u;
    return (short)(u >> 16);
}

// ---------------- ROI max-pool: x (1,512,37,50) -> A (128, 25088) bf16 ----------------
__global__ void pool_kernel(const float* __restrict__ x, const float* __restrict__ rois,
                            const int* __restrict__ ridx, short* __restrict__ A) {
    const int r = blockIdx.x;
    const int y1 = (int)floorf(rois[r * 4 + 0] * 0.0625f);
    const int x1 = (int)floorf(rois[r * 4 + 1] * 0.0625f);
    const int y2 = (int)floorf(rois[r * 4 + 2] * 0.0625f);
    const int x2 = (int)floorf(rois[r * 4 + 3] * 0.0625f);
    const int h = y2 - y1 + 1, w = x2 - x1 + 1;
    const float* feat = x + (size_t)ridx[r] * (512 * 37 * 50);
    for (int t = blockIdx.y * 256 + threadIdx.x; t < 25088; t += 2048) {
        const int c = t / 49, b = t % 49, i = b / 7, j = b % 7;
        const int ys = y1 + (i * h) / 7, ye = y1 + ((i + 1) * h + 6) / 7;
        const int xs = x1 + (j * w) / 7, xe = x1 + ((j + 1) * w + 6) / 7;
        const float* f = feat + c * 1850;
        float m = -1e30f;
        for (int yy = ys; yy < ye; yy++)
            for (int xx = xs; xx < xe; xx++)
                m = fmaxf(m, f[yy * 50 + xx]);
        A[(size_t)r * 25088 + t] = f2bf(m);
    }
}

// ---------------- pack w_cls (4096x84) + w_score (4096x21) -> whd (4096x128) ----------------
__global__ void build_whd(const float* __restrict__ wc, const float* __restrict__ wsc,
                          float* __restrict__ whd) {
    const int idx = blockIdx.x * 256 + threadIdx.x;   // < 4096*128
    const int k = idx >> 7, n = idx & 127;
    float v = 0.f;
    if (n < 84) v = wc[k * 84 + n];
    else if (n < 105) v = wsc[k * 21 + (n - 84)];
    whd[idx] = v;
}

// ---------------- generic M=128 GEMM: part[slab] += A(128xK bf16) @ W(KxN fp32) ----------------
// block: 256 thr (4 waves). wave handles 32 rows x 64 cols: 2 M-tiles x 4 N-frags, 8 MFMA/step.
// A-frags: direct global short8 loads (A is small, L2/L3-resident).
// B-frags: 32 direct global dword loads/step, converted fp32->bf16 in-register.
// Register ping-pong prefetch: step s+1's loads issue before step s's MFMAs.
__global__ __launch_bounds__(256, 2)
void gemm128(const short* __restrict__ A, const float* __restrict__ W,
             float* __restrict__ part, int K, int N, int kchunk) {
    const int lane = threadIdx.x & 63;
    const int wave = threadIdx.x >> 6;
    const int l15 = lane & 15;
    const int quad = lane >> 4;
    const int n_base = blockIdx.x * 64;
    const int kb = blockIdx.y * kchunk;
    const int m0 = wave * 32;

    f32x4 acc[2][4] = {};

    const short* a0 = A + (size_t)(m0 + l15) * K + kb + quad * 8;
    const float* w0 = W + (size_t)(kb + quad * 8) * N + n_base + l15;
    const int steps = kchunk >> 5;

    auto loadA = [&](int s, short8* af) {
        const short* p = a0 + s * 32;
        af[0] = *(const short8*)p;
        af[1] = *(const short8*)(p + (size_t)16 * K);
    };
    auto loadB = [&](int s, short8* bf) {
#pragma unroll
        for (int fn = 0; fn < 4; fn++) {
            const float* p = w0 + (size_t)s * 32 * N + fn * 16;
            short8 v;
#pragma unroll
            for (int j = 0; j < 8; j++) v[j] = f2bf(p[(size_t)j * N]);
            bf[fn] = v;
        }
    };
    auto domfma = [&](short8* af, short8* bf) {
#pragma unroll
        for (int t = 0; t < 2; t++)
#pragma unroll
            for (int fn = 0; fn < 4; fn++)
                acc[t][fn] = __builtin_amdgcn_mfma_f32_16x16x32_bf16(af[t], bf[fn], acc[t][fn], 0, 0, 0);
    };

    short8 aC[2], bC[4], aN[2], bN[4];
    loadA(0, aC); loadB(0, bC);
    int s = 1;
    for (; s + 1 < steps; s += 2) {
        loadA(s, aN); loadB(s, bN);
        domfma(aC, bC);
        loadA(s + 1, aC); loadB(s + 1, bC);
        domfma(aN, bN);
    }
    if (s < steps) {
        loadA(s, aN); loadB(s, bN);
        domfma(aC, bC);
        domfma(aN, bN);
    } else {
        domfma(aC, bC);
    }

    float* out = part + (size_t)blockIdx.y * 128 * N;
#pragma unroll
    for (int t = 0; t < 2; t++)
#pragma unroll
        for (int fn = 0; fn < 4; fn++)
#pragma unroll
            for (int r = 0; r < 4; r++) {
                const int row = m0 + 16 * t + quad * 4 + r;
                const int col = n_base + fn * 16 + l15;
                out[(size_t)row * N + col] = acc[t][fn][r];
            }
}

// ---------------- slab-reduce + bias + relu -> bf16 activations ----------------
__global__ void reduce_fc(const float* __restrict__ part, const float* __restrict__ bias,
                          short* __restrict__ out, int N, int nslabs) {
    const int idx = blockIdx.x * 256 + threadIdx.x;   // < 128*N
    const int n = idx % N;
    float s = bias[n];
    for (int sl = 0; sl < nslabs; sl++) s += part[(size_t)sl * 128 * N + idx];
    s = fmaxf(s, 0.f);
    out[idx] = f2bf(s);
}

// ---------------- heads slab-reduce + bias -> d_out (cls 128x84 | score 128x21) ----------------
__global__ void reduce_heads(const float* __restrict__ part, const float* __restrict__ bc,
                             const float* __restrict__ bsc, float* __restrict__ out) {
    const int idx = blockIdx.x * 256 + threadIdx.x;
    if (idx >= 128 * 105) return;
    const int m = idx / 105, n = idx % 105;
    float s = 0.f;
    for (int sl = 0; sl < 16; sl++) s += part[sl * (128 * NHD) + m * NHD + n];
    if (n < 84) out[m * 84 + n] = s + bc[n];
    else out[128 * 84 + m * 21 + (n - 84)] = s + bsc[n - 84];
}

extern "C" void kernel_launch(void* const* d_in, const int* in_sizes, int n_in,
                              void* d_out, int out_size, void* d_ws, size_t ws_size,
                              hipStream_t stream) {
    const float* x    = (const float*)d_in[0];
    const float* rois = (const float*)d_in[1];
    const int*   ridx = (const int*)d_in[2];
    const float* w6   = (const float*)d_in[3];
    const float* b6   = (const float*)d_in[4];
    const float* w7   = (const float*)d_in[5];
    const float* b7   = (const float*)d_in[6];
    const float* wc   = (const float*)d_in[7];
    const float* bc   = (const float*)d_in[8];
    const float* wsc  = (const float*)d_in[9];
    const float* bsc  = (const float*)d_in[10];
    float* out = (float*)d_out;

    char* base = (char*)d_ws;
    short* Apool = (short*)base;                         // 128*25088*2 = 6,422,528 B
    float* whd   = (float*)(base + 6422528);             // 4096*128*4  = 2,097,152 B
    short* fc6b  = (short*)(base + 8519680);             // 128*4096*2  = 1,048,576 B
    short* fc7b  = (short*)(base + 9568256);             // 128*4096*2  = 1,048,576 B
    float* slabs = (float*)(base + 10616832);            // max 8*128*4096*4 = 16 MB

    pool_kernel<<<dim3(128, 8), 256, 0, stream>>>(x, rois, ridx, Apool);
    build_whd<<<2048, 256, 0, stream>>>(wc, wsc, whd);

    // fc6: K=25088, N=4096, 8 k-slabs -> 512 blocks
    gemm128<<<dim3(64, 8), 256, 0, stream>>>(Apool, w6, slabs, 25088, 4096, 3136);
    reduce_fc<<<2048, 256, 0, stream>>>(slabs, b6, fc6b, 4096, 8);

    // fc7: K=4096, N=4096, 4 k-slabs -> 256 blocks
    gemm128<<<dim3(64, 4), 256, 0, stream>>>(fc6b, w7, slabs, 4096, 4096, 1024);
    reduce_fc<<<2048, 256, 0, stream>>>(slabs, b7, fc7b, 4096, 4);

    // heads: K=4096, N=128 (padded), 16 k-slabs -> 32 blocks
    gemm128<<<dim3(2, 16), 256, 0, stream>>>(fc7b, whd, slabs, 4096, 128, 256);
    reduce_heads<<<53, 256, 0, stream>>>(slabs, bc, bsc, out);
}

// Round 2
// 701.181 us; speedup vs baseline: 1.2991x; 1.2991x over previous
//
#include <hip/hip_runtime.h>
#include <hip/hip_bf16.h>

// VGG16 ROI head: roi_pool -> fc6(relu) -> fc7(relu) -> {cls, score}
// Weight-streaming memory-bound (fc6 W = 411 MB fp32). bf16 MFMA 16x16x32.
// R2: LDS-staged GEMM. Stage W fp32->bf16 once per tile (convert-on-write),
// transposed LDS layout [64 n][SK=34 k] so B-fragments are k-contiguous dword
// reads. Double-buffered LDS, 1 barrier/step, global prefetch 2 steps ahead,
// loop unrolled x2 so all buffer indices are compile-time constants.

typedef short short8 __attribute__((ext_vector_type(8)));   // 8 x bf16 bits
typedef float f32x4 __attribute__((ext_vector_type(4)));
typedef int   int4v __attribute__((ext_vector_type(4)));

#define TN 64
#define SK 34      // LDS k-stride in shorts (32 + 2 pad: breaks bank aliasing)

static __device__ inline unsigned bfround(float f) {   // fp32 -> bf16 bits (round-half-up)
    return __builtin_bit_cast(unsigned, f) + 0x8000u;
}
static __device__ inline short f2bf(float f) { return (short)(bfround(f) >> 16); }

// ---------------- ROI max-pool: x (1,512,37,50) -> A (128, 25088) bf16 ----------------
__global__ void pool_kernel(const float* __restrict__ x, const float* __restrict__ rois,
                            const int* __restrict__ ridx, short* __restrict__ A) {
    const int r = blockIdx.x;
    const int y1 = (int)floorf(rois[r * 4 + 0] * 0.0625f);
    const int x1 = (int)floorf(rois[r * 4 + 1] * 0.0625f);
    const int y2 = (int)floorf(rois[r * 4 + 2] * 0.0625f);
    const int x2 = (int)floorf(rois[r * 4 + 3] * 0.0625f);
    const int h = y2 - y1 + 1, w = x2 - x1 + 1;
    const float* feat = x + (size_t)ridx[r] * (512 * 37 * 50);
    for (int t = blockIdx.y * 256 + threadIdx.x; t < 25088; t += 2048) {
        const int c = t / 49, b = t % 49, i = b / 7, j = b % 7;
        const int ys = y1 + (i * h) / 7, ye = y1 + ((i + 1) * h + 6) / 7;
        const int xs = x1 + (j * w) / 7, xe = x1 + ((j + 1) * w + 6) / 7;
        const float* f = feat + c * 1850;
        float m = -1e30f;
        for (int yy = ys; yy < ye; yy++)
            for (int xx = xs; xx < xe; xx++)
                m = fmaxf(m, f[yy * 50 + xx]);
        A[(size_t)r * 25088 + t] = f2bf(m);
    }
}

// ---------------- pack w_cls (4096x84) + w_score (4096x21) -> whd (4096x128) ----------------
__global__ void build_whd(const float* __restrict__ wc, const float* __restrict__ wsc,
                          float* __restrict__ whd) {
    const int idx = blockIdx.x * 256 + threadIdx.x;   // < 4096*128
    const int k = idx >> 7, n = idx & 127;
    float v = 0.f;
    if (n < 84) v = wc[k * 84 + n];
    else if (n < 105) v = wsc[k * 21 + (n - 84)];
    whd[idx] = v;
}

// ---------------- M=128 GEMM: part[slab] = A(128xK bf16) @ W(KxN fp32) ----------------
// block: 256 thr (4 waves). Block tile: 128 m x 64 n. K-step = 32.
// Staging thread map: kp = tid>>4 (k-pair 0..15 -> k = 2kp,2kp+1), nb = (tid&15)*4.
// Each thread: 2 x float4 (rows k,k+1; cols nb..nb+3), convert, pack k-pairs
// into dwords, write transposed LDS [n][k].  Requires steps even and >= 4.
__global__ __launch_bounds__(256, 4)
void gemm128(const short* __restrict__ A, const float* __restrict__ W,
             float* __restrict__ part, int K, int N, int kchunk) {
    __shared__ short lds[2][TN * SK];

    const int tid = threadIdx.x;
    const int lane = tid & 63, wave = tid >> 6;
    const int l15 = lane & 15, quad = lane >> 4;
    const int n_base = blockIdx.x * TN;
    const int kb = blockIdx.y * kchunk;
    const int m0 = wave * 32;
    const int steps = kchunk >> 5;

    const int kp = tid >> 4;          // 0..15
    const int nb = (tid & 15) * 4;    // 0,4,...,60
    const float* gW = W + (size_t)(kb + 2 * kp) * N + n_base + nb;
    const short* gA = A + (size_t)(m0 + l15) * K + kb + quad * 8;

    f32x4 acc[2][4] = {};
    f32x4 wset[2][2];    // [stage][k-row of pair]
    short8 aset[2][2];   // [stage][m-tile]

    auto wload = [&](int s, int c) {
        const float* p = gW + (size_t)s * 32 * N;
        wset[c][0] = *(const f32x4*)p;
        wset[c][1] = *(const f32x4*)(p + N);
    };
    auto aload = [&](int s, int c) {
        const short* p = gA + (size_t)s * 32;
        aset[c][0] = *(const short8*)p;
        aset[c][1] = *(const short8*)(p + (size_t)16 * K);
    };
    auto stage = [&](int c, int buf) {   // convert wset[c] -> lds[buf]
        unsigned* dst = (unsigned*)&lds[buf][0];
#pragma unroll
        for (int i = 0; i < 4; i++) {
            unsigned lo = bfround(wset[c][0][i]) >> 16;
            unsigned hi = bfround(wset[c][1][i]) & 0xffff0000u;
            dst[((nb + i) * SK + 2 * kp) >> 1] = lo | hi;
        }
    };

    // prologue: stages 0,1 in flight; stage 0 into buf 0
    wload(0, 0); wload(1, 1);
    aload(0, 0); aload(1, 1);
    stage(0, 0);

    for (int s = 0; s < steps; s += 2) {
#pragma unroll
        for (int half = 0; half < 2; half++) {
            const int ss = s + half;
            const int C = half;          // compile-time 0/1
            if (ss + 2 < steps) wload(ss + 2, C);
            __syncthreads();
            const short* buf = &lds[C][0];
#pragma unroll
            for (int fn = 0; fn < 4; fn++) {
                const int* src = (const int*)(buf + (fn * 16 + l15) * SK + quad * 8);
                int4v t;
                t[0] = src[0]; t[1] = src[1]; t[2] = src[2]; t[3] = src[3];
                short8 bfr = __builtin_bit_cast(short8, t);
                acc[0][fn] = __builtin_amdgcn_mfma_f32_16x16x32_bf16(aset[C][0], bfr, acc[0][fn], 0, 0, 0);
                acc[1][fn] = __builtin_amdgcn_mfma_f32_16x16x32_bf16(aset[C][1], bfr, acc[1][fn], 0, 0, 0);
            }
            if (ss + 2 < steps) aload(ss + 2, C);
            if (ss + 1 < steps) stage(C ^ 1, C ^ 1);
        }
    }

    float* out = part + (size_t)blockIdx.y * 128 * N;
#pragma unroll
    for (int t = 0; t < 2; t++)
#pragma unroll
        for (int fn = 0; fn < 4; fn++)
#pragma unroll
            for (int r = 0; r < 4; r++) {
                const int row = m0 + 16 * t + quad * 4 + r;
                const int col = n_base + fn * 16 + l15;
                out[(size_t)row * N + col] = acc[t][fn][r];
            }
}

// ---------------- slab-reduce + bias + relu -> bf16 activations ----------------
__global__ void reduce_fc(const float* __restrict__ part, const float* __restrict__ bias,
                          short* __restrict__ out, int N, int nslabs) {
    const int idx = blockIdx.x * 256 + threadIdx.x;   // < 128*N
    const int n = idx % N;
    float s = bias[n];
    for (int sl = 0; sl < nslabs; sl++) s += part[(size_t)sl * 128 * N + idx];
    s = fmaxf(s, 0.f);
    out[idx] = f2bf(s);
}

// ---------------- heads slab-reduce + bias -> d_out (cls 128x84 | score 128x21) ----------------
__global__ void reduce_heads(const float* __restrict__ part, const float* __restrict__ bc,
                             const float* __restrict__ bsc, float* __restrict__ out) {
    const int idx = blockIdx.x * 256 + threadIdx.x;
    if (idx >= 128 * 105) return;
    const int m = idx / 105, n = idx % 105;
    float s = 0.f;
    for (int sl = 0; sl < 32; sl++) s += part[sl * (128 * 128) + m * 128 + n];
    if (n < 84) out[m * 84 + n] = s + bc[n];
    else out[128 * 84 + m * 21 + (n - 84)] = s + bsc[n - 84];
}

extern "C" void kernel_launch(void* const* d_in, const int* in_sizes, int n_in,
                              void* d_out, int out_size, void* d_ws, size_t ws_size,
                              hipStream_t stream) {
    const float* x    = (const float*)d_in[0];
    const float* rois = (const float*)d_in[1];
    const int*   ridx = (const int*)d_in[2];
    const float* w6   = (const float*)d_in[3];
    const float* b6   = (const float*)d_in[4];
    const float* w7   = (const float*)d_in[5];
    const float* b7   = (const float*)d_in[6];
    const float* wc   = (const float*)d_in[7];
    const float* bc   = (const float*)d_in[8];
    const float* wsc  = (const float*)d_in[9];
    const float* bsc  = (const float*)d_in[10];
    float* out = (float*)d_out;

    char* base = (char*)d_ws;
    short* Apool = (short*)base;                         // 128*25088*2 = 6,422,528 B
    float* whd   = (float*)(base + 6422528);             // 4096*128*4  = 2,097,152 B
    short* fc6b  = (short*)(base + 8519680);             // 128*4096*2  = 1,048,576 B
    short* fc7b  = (short*)(base + 9568256);             // 128*4096*2  = 1,048,576 B
    float* slabs = (float*)(base + 10616832);            // max 8*128*4096*4 = 16 MB

    pool_kernel<<<dim3(128, 8), 256, 0, stream>>>(x, rois, ridx, Apool);
    build_whd<<<2048, 256, 0, stream>>>(wc, wsc, whd);

    // fc6: K=25088, N=4096, 8 k-slabs (kchunk 3136 -> 98 steps), 512 blocks
    gemm128<<<dim3(64, 8), 256, 0, stream>>>(Apool, w6, slabs, 25088, 4096, 3136);
    reduce_fc<<<2048, 256, 0, stream>>>(slabs, b6, fc6b, 4096, 8);

    // fc7: K=4096, N=4096, 8 k-slabs (kchunk 512 -> 16 steps), 512 blocks
    gemm128<<<dim3(64, 8), 256, 0, stream>>>(fc6b, w7, slabs, 4096, 4096, 512);
    reduce_fc<<<2048, 256, 0, stream>>>(slabs, b7, fc7b, 4096, 8);

    // heads: K=4096, N=128 (padded), 32 k-slabs (kchunk 128 -> 4 steps), 64 blocks
    gemm128<<<dim3(2, 32), 256, 0, stream>>>(fc7b, whd, slabs, 4096, 128, 128);
    reduce_heads<<<53, 256, 0, stream>>>(slabs, bc, bsc, out);
}